// Round 5
// baseline (83.237 us; speedup 1.0000x reference)
//
#include <hip/hip_runtime.h>

#define BATCH  4
#define NPTS   4096
#define NSKEL  100
#define KNN    10
#define SPLIT  32                 // lanes per query-group
#define CPT    (NPTS / SPLIT)     // 128 candidates per thread
#define QPB    64                 // 32 groups/block * 2 queries/group
#define BIG    3.0e38f

__device__ __forceinline__ float med3f(float a, float b, float c) {
#if __has_builtin(__builtin_amdgcn_fmed3f)
    return __builtin_amdgcn_fmed3f(a, b, c);
#else
    float d;
    asm("v_med3_f32 %0, %1, %2, %3" : "=v"(d) : "v"(a), "v"(b), "v"(c));
    return d;
#endif
}

#define CE(a,i,j) do { float _lo = fminf(a[i],a[j]); a[j] = fmaxf(a[i],a[j]); a[i] = _lo; } while (0)

// Merge my ascending 10-list with lane^mask's via bitonic half-cleaner (keep
// the 10 smallest of the 20), then re-sort with the 15-CE network (validated
// R3/R4: absmax 0). After a sorted round, all participating lanes hold
// elementwise-identical lists.
__device__ __forceinline__ void merge_round(float l[KNN], int mask) {
    float c[KNN];
#pragma unroll
    for (int i = 0; i < KNN; ++i) {
        float o = __shfl_xor(l[KNN - 1 - i], mask, 64);
        c[i] = fminf(l[i], o);
    }
    CE(c,0,8); CE(c,1,9);
    CE(c,2,6); CE(c,3,7); CE(c,4,8); CE(c,5,9);
    CE(c,2,4); CE(c,3,5); CE(c,6,8); CE(c,7,9); CE(c,0,1);
    CE(c,2,3); CE(c,4,5); CE(c,6,7); CE(c,8,9);
#pragma unroll
    for (int i = 0; i < KNN; ++i) l[i] = c[i];
}

__global__ __launch_bounds__(1024, 4) void voronoi_kernel(const float* __restrict__ xyz,
                                                          const float* __restrict__ skel,
                                                          float* __restrict__ out) {
    __shared__ float4 spts[NPTS];    // x,y,z,|p|^2  (64 KB)
    __shared__ float4 sskl[NSKEL];
    __shared__ float  part[16];

    const int tid = threadIdx.x;
    const int b   = blockIdx.x >> 6;           // 64 blocks per batch
    const int qb  = (blockIdx.x & 63) * QPB;   // 64 queries per block
    const float* xb = xyz  + (size_t)b * NPTS * 6;
    const float* sb = skel + (size_t)b * NSKEL * 3;

    // Stage 2 points per iter via 3 coalesced float4 loads (2 iterations)
    for (int p2 = tid; p2 < NPTS / 2; p2 += 1024) {
        const float4* row = (const float4*)(xb + p2 * 12);
        float4 A = row[0], Bv = row[1], Cv = row[2];
        int i0 = 2 * p2;
        spts[i0]     = make_float4(A.x, A.y, A.z,
                                   fmaf(A.z, A.z, fmaf(A.y, A.y, A.x * A.x)));
        spts[i0 + 1] = make_float4(Bv.z, Bv.w, Cv.x,
                                   fmaf(Cv.x, Cv.x, fmaf(Bv.w, Bv.w, Bv.z * Bv.z)));
    }
    if (tid < NSKEL) {
        float x = sb[tid*3+0], y = sb[tid*3+1], z = sb[tid*3+2];
        sskl[tid] = make_float4(x, y, z, x*x + y*y + z*z);
    }
    __syncthreads();

    const int split = tid & 31;
    const int group = tid >> 5;                // 0..31
    const int q0i   = qb + group * 2;
    const float4 Q0 = spts[q0i];
    const float4 Q1 = spts[q0i + 1];
    // score = |c|^2 - 2 q.c  (monotone map of d2; d2 gap == score gap)
    const float n0x = -2.f*Q0.x, n0y = -2.f*Q0.y, n0z = -2.f*Q0.z;
    const float n1x = -2.f*Q1.x, n1y = -2.f*Q1.y, n1z = -2.f*Q1.z;

    float l0[KNN], l1[KNN];
#pragma unroll
    for (int k = 0; k < KNN; ++k) { l0[k] = BIG; l1[k] = BIG; }

    const int jb = split * CPT;
    const float4* chunk = spts + jb;   // fixed base: all reads fold to imm offsets

    float4 A4[4], B4[4];
#pragma unroll
    for (int u = 0; u < 4; ++u) A4[u] = chunk[u];

    auto PROC = [&](const float4* buf, int t) {
#pragma unroll
        for (int u = 0; u < 4; ++u) {
            float4 cc = buf[u];
            float s0 = fmaf(n0z, cc.z, fmaf(n0y, cc.y, fmaf(n0x, cc.x, cc.w)));
            float s1 = fmaf(n1z, cc.z, fmaf(n1y, cc.y, fmaf(n1x, cc.x, cc.w)));
            unsigned j = (unsigned)(jb + t + u);
            float f0 = __uint_as_float((__float_as_uint(s0) & 0xFFFFF000u) | j);
            float f1 = __uint_as_float((__float_as_uint(s1) & 0xFFFFF000u) | j);
#pragma unroll
            for (int k = KNN - 1; k >= 1; --k) l0[k] = med3f(f0, l0[k-1], l0[k]);
            l0[0] = fminf(f0, l0[0]);
#pragma unroll
            for (int k = KNN - 1; k >= 1; --k) l1[k] = med3f(f1, l1[k-1], l1[k]);
            l1[0] = fminf(f1, l1[0]);
        }
    };

    // Double-buffered scan: next 4 candidates' ds_read_b128 issue before
    // processing the current 4.
#pragma unroll 1
    for (int t = 0; t < CPT; t += 8) {
#pragma unroll
        for (int u = 0; u < 4; ++u) B4[u] = chunk[t + 4 + u];
        PROC(A4, t);
        if (t + 8 < CPT) {
#pragma unroll
            for (int u = 0; u < 4; ++u) A4[u] = chunk[t + 8 + u];
        }
        PROC(B4, t + 4);
    }

    // Merge the 32 lanes' lists; ALL rounds sorted so every lane ends with
    // the elementwise-identical ascending top-10 (needed for distribution).
    merge_round(l0, 1); merge_round(l0, 2); merge_round(l0, 4);
    merge_round(l0, 8); merge_round(l0, 16);
    merge_round(l1, 1); merge_round(l1, 2); merge_round(l1, 4);
    merge_round(l1, 8); merge_round(l1, 16);

    // ---- distributed changingrate: lane (parity sel, kk) handles neighbor kk
    const int sel = split & 1;
    const int kk  = split >> 1;       // 0..15
    const int myq = q0i + sel;
    float crk = 0.0f;
    if (kk < KNN) {
        float mlk = BIG;
#pragma unroll
        for (int k = 0; k < KNN; ++k) {
            float v = sel ? l1[k] : l0[k];
            mlk = (kk == k) ? v : mlk;     // static-index select (no scratch)
        }
        int j = (int)(__float_as_uint(mlk) & 0xFFFu);
        float nx = xb[myq*6+3], ny = xb[myq*6+4], nz = xb[myq*6+5];
        float mx = xb[j*6+3],  my_ = xb[j*6+4],  mz = xb[j*6+5];
        float cx = ny*mz - nz*my_;
        float cy = nz*mx - nx*mz;
        float cz = nx*my_ - ny*mx;
        float c1 = sqrtf(cx*cx + cy*cy + cz*cz);
        float px = nx*mx, py = ny*my_, pz = nz*mz;
        float c2 = sqrtf(px*px + py*py + pz*pz);
        crk = fminf(c1, c2);
    }
#pragma unroll
    for (int m = 2; m <= 16; m <<= 1) crk += __shfl_xor(crk, m, 64);

    // ---- top-2 skeleton scores for my parity query (16-lane split) ----
    const float nqx = sel ? n1x : n0x;
    const float nqy = sel ? n1y : n0y;
    const float nqz = sel ? n1z : n0z;
    float t0v = BIG, t1v = BIG;
    for (int m = kk; m < NSKEL; m += 16) {
        float4 c = sskl[m];
        float s = fmaf(nqz, c.z, fmaf(nqy, c.y, fmaf(nqx, c.x, c.w)));
        t1v = med3f(s, t0v, t1v);    // uses old t0v
        t0v = fminf(s, t0v);
    }
#pragma unroll
    for (int m = 2; m <= 16; m <<= 1) {
        float o0 = __shfl_xor(t0v, m, 64);
        float o1 = __shfl_xor(t1v, m, 64);
        float nv = fminf(fmaxf(t0v, o0), fminf(t1v, o1));
        t0v = fminf(t0v, o0); t1v = nv;
    }
    // owners: split 0 -> q0, split 1 -> q1
    float contrib = (split < 2) ? crk * (t1v - t0v) : 0.0f;

#pragma unroll
    for (int o = 32; o > 0; o >>= 1) contrib += __shfl_down(contrib, o);
    if ((tid & 63) == 0) part[tid >> 6] = contrib;
    __syncthreads();
    if (tid == 0) {
        float s = 0.0f;
#pragma unroll
        for (int i = 0; i < 16; ++i) s += part[i];
        atomicAdd(out, s);
    }

    // ---- skeleton self-NN term, one block per batch ----
    if ((blockIdx.x & 63) == 0) {
        float v = 0.0f;
        if (tid < NSKEL) {
            float4 sq = sskl[tid];
            float b0 = BIG, b1 = BIG; int i0 = 0, i1 = 0;
            for (int jj = 0; jj < NSKEL; ++jj) {
                float4 c = sskl[jj];
                float s = c.w - 2.0f*(sq.x*c.x + sq.y*c.y + sq.z*c.z);
                if (s < b0)      { b1 = b0; i1 = i0; b0 = s; i0 = jj; }
                else if (s < b1) { b1 = s; i1 = jj; }
            }
            float4 c = sskl[i1];                 // knn_skele[..., 1]
            float dx = sq.x - c.x, dy = sq.y - c.y, dz = sq.z - c.z;
            v = sqrtf(dx*dx + dy*dy + dz*dz);
        }
#pragma unroll
        for (int o = 32; o > 0; o >>= 1) v += __shfl_down(v, o);
        if ((tid & 63) == 0 && tid < 128) atomicAdd(out, -0.5f * v);
    }
}

extern "C" void kernel_launch(void* const* d_in, const int* in_sizes, int n_in,
                              void* d_out, int out_size, void* d_ws, size_t ws_size,
                              hipStream_t stream) {
    const float* xyz  = (const float*)d_in[0];
    // d_in[1] = num_class (== NSKEL), compile-time constant here
    const float* skel = (const float*)d_in[2];
    float* out = (float*)d_out;

    hipMemsetAsync(out, 0, sizeof(float), stream);
    voronoi_kernel<<<BATCH * 64, 1024, 0, stream>>>(xyz, skel, out);
}

// Round 6
// 52.539 us; speedup vs baseline: 1.5843x; 1.5843x over previous
//
#include <hip/hip_runtime.h>

#define BATCH  4
#define NPTS   4096
#define NSKEL  100
#define KNN    10
#define SPLIT  32                 // lanes per query-group
#define CPT    (NPTS / SPLIT)     // 128 candidates per thread
#define CPAD   (CPT + 1)          // padded chunk stride (bank de-conflict)
#define QPB    64                 // 32 groups/block * 2 queries/group
#define BIG    3.0e38f

__device__ __forceinline__ float med3f(float a, float b, float c) {
#if __has_builtin(__builtin_amdgcn_fmed3f)
    return __builtin_amdgcn_fmed3f(a, b, c);
#else
    float d;
    asm("v_med3_f32 %0, %1, %2, %3" : "=v"(d) : "v"(a), "v"(b), "v"(c));
    return d;
#endif
}

#define CE(a,i,j) do { float _lo = fminf(a[i],a[j]); a[j] = fmaxf(a[i],a[j]); a[i] = _lo; } while (0)

// Merge my ascending 10-list with lane^mask's via bitonic half-cleaner (keep
// the 10 smallest of 20), then re-sort with the 15-CE network (validated
// R3-R5: absmax 0). After a round, lanes i and i^mask hold identical lists.
__device__ __forceinline__ void merge_round(float l[KNN], int mask) {
    float c[KNN];
#pragma unroll
    for (int i = 0; i < KNN; ++i) {
        float o = __shfl_xor(l[KNN - 1 - i], mask, 64);
        c[i] = fminf(l[i], o);
    }
    CE(c,0,8); CE(c,1,9);
    CE(c,2,6); CE(c,3,7); CE(c,4,8); CE(c,5,9);
    CE(c,2,4); CE(c,3,5); CE(c,6,8); CE(c,7,9); CE(c,0,1);
    CE(c,2,3); CE(c,4,5); CE(c,6,7); CE(c,8,9);
#pragma unroll
    for (int i = 0; i < KNN; ++i) l[i] = c[i];
}

// padded LDS index for global point id j (chunk = j>>7 gets +1 float4 each)
#define PIDX(j) ((j) + ((j) >> 7))

__global__ __launch_bounds__(1024, 4) void voronoi_kernel(const float* __restrict__ xyz,
                                                          const float* __restrict__ skel,
                                                          float* __restrict__ out) {
    __shared__ float4 spts[NPTS + SPLIT];  // padded chunks, 64.5 KB
    __shared__ float4 sskl[NSKEL];
    __shared__ float  part[16];

    const int tid = threadIdx.x;
    const int b   = blockIdx.x >> 6;           // 64 blocks per batch
    const int qb  = (blockIdx.x & 63) * QPB;   // 64 queries per block
    const float* xb = xyz  + (size_t)b * NPTS * 6;
    const float* sb = skel + (size_t)b * NSKEL * 3;

    // Stage 2 points per iter via 3 coalesced float4 loads (2 iterations)
    for (int p2 = tid; p2 < NPTS / 2; p2 += 1024) {
        const float4* row = (const float4*)(xb + p2 * 12);
        float4 A = row[0], Bv = row[1], Cv = row[2];
        int i0 = 2 * p2;
        spts[PIDX(i0)]     = make_float4(A.x, A.y, A.z,
                                         fmaf(A.z, A.z, fmaf(A.y, A.y, A.x * A.x)));
        spts[PIDX(i0 + 1)] = make_float4(Bv.z, Bv.w, Cv.x,
                                         fmaf(Cv.x, Cv.x, fmaf(Bv.w, Bv.w, Bv.z * Bv.z)));
    }
    if (tid < NSKEL) {
        float x = sb[tid*3+0], y = sb[tid*3+1], z = sb[tid*3+2];
        sskl[tid] = make_float4(x, y, z, x*x + y*y + z*z);
    }
    __syncthreads();

    const int split = tid & 31;
    const int group = tid >> 5;                // 0..31
    const int q0i   = qb + group * 2;
    const float4 Q0 = spts[PIDX(q0i)];
    const float4 Q1 = spts[PIDX(q0i + 1)];
    // score = |c|^2 - 2 q.c  (monotone map of d2; d2 gap == score gap)
    const float n0x = -2.f*Q0.x, n0y = -2.f*Q0.y, n0z = -2.f*Q0.z;
    const float n1x = -2.f*Q1.x, n1y = -2.f*Q1.y, n1z = -2.f*Q1.z;

    float l0[KNN], l1[KNN];
#pragma unroll
    for (int k = 0; k < KNN; ++k) { l0[k] = BIG; l1[k] = BIG; }

    const int jb = split * CPT;
    const float4* chunk = spts + split * CPAD;  // base bank-quad = split%8: conflict-free

    float4 A4[4], B4[4];
#pragma unroll
    for (int u = 0; u < 4; ++u) A4[u] = chunk[u];

    auto PROC = [&](const float4* buf, int t) {
#pragma unroll
        for (int u = 0; u < 4; ++u) {
            float4 cc = buf[u];
            float s0 = fmaf(n0z, cc.z, fmaf(n0y, cc.y, fmaf(n0x, cc.x, cc.w)));
            float s1 = fmaf(n1z, cc.z, fmaf(n1y, cc.y, fmaf(n1x, cc.x, cc.w)));
            unsigned j = (unsigned)(jb + t + u);
            float f0 = __uint_as_float((__float_as_uint(s0) & 0xFFFFF000u) | j);
            float f1 = __uint_as_float((__float_as_uint(s1) & 0xFFFFF000u) | j);
#pragma unroll
            for (int k = KNN - 1; k >= 1; --k) l0[k] = med3f(f0, l0[k-1], l0[k]);
            l0[0] = fminf(f0, l0[0]);
#pragma unroll
            for (int k = KNN - 1; k >= 1; --k) l1[k] = med3f(f1, l1[k-1], l1[k]);
            l1[0] = fminf(f1, l1[0]);
        }
    };

    // Double-buffered scan: next 4 candidates' ds_read_b128 issue before
    // processing the current 4.
#pragma unroll 1
    for (int t = 0; t < CPT; t += 8) {
#pragma unroll
        for (int u = 0; u < 4; ++u) B4[u] = chunk[t + 4 + u];
        PROC(A4, t);
        if (t + 8 < CPT) {
#pragma unroll
            for (int u = 0; u < 4; ++u) A4[u] = chunk[t + 8 + u];
        }
        PROC(B4, t + 4);
    }

    // ---- merge: 1 paired round, then parity-split single-list rounds ----
    merge_round(l0, 1);
    merge_round(l1, 1);
    const int sel = split & 1;
    float ml[KNN];
#pragma unroll
    for (int k = 0; k < KNN; ++k) ml[k] = sel ? l1[k] : l0[k];
    merge_round(ml, 2); merge_round(ml, 4); merge_round(ml, 8); merge_round(ml, 16);
    // now every even lane holds q0's sorted top-10, every odd lane q1's

    // ---- distributed changingrate: lane (sel, kk) handles neighbor kk ----
    const int kk  = split >> 1;       // 0..15
    const int myq = q0i + sel;
    float crk = 0.0f;
    if (kk < KNN) {
        float mlk = BIG;
#pragma unroll
        for (int k = 0; k < KNN; ++k) mlk = (kk == k) ? ml[k] : mlk;  // static select
        int j = (int)(__float_as_uint(mlk) & 0xFFFu);
        float nx = xb[myq*6+3], ny = xb[myq*6+4], nz = xb[myq*6+5];
        float mx = xb[j*6+3],  my_ = xb[j*6+4],  mz = xb[j*6+5];
        float cx = ny*mz - nz*my_;
        float cy = nz*mx - nx*mz;
        float cz = nx*my_ - ny*mx;
        float c1 = sqrtf(cx*cx + cy*cy + cz*cz);
        float px = nx*mx, py = ny*my_, pz = nz*mz;
        float c2 = sqrtf(px*px + py*py + pz*pz);
        crk = fminf(c1, c2);
    }
#pragma unroll
    for (int m = 2; m <= 16; m <<= 1) crk += __shfl_xor(crk, m, 64);

    // ---- top-2 skeleton scores for my parity query (16-lane split) ----
    const float nqx = sel ? n1x : n0x;
    const float nqy = sel ? n1y : n0y;
    const float nqz = sel ? n1z : n0z;
    float t0v = BIG, t1v = BIG;
    for (int m = kk; m < NSKEL; m += 16) {
        float4 c = sskl[m];
        float s = fmaf(nqz, c.z, fmaf(nqy, c.y, fmaf(nqx, c.x, c.w)));
        t1v = med3f(s, t0v, t1v);    // uses old t0v
        t0v = fminf(s, t0v);
    }
#pragma unroll
    for (int m = 2; m <= 16; m <<= 1) {
        float o0 = __shfl_xor(t0v, m, 64);
        float o1 = __shfl_xor(t1v, m, 64);
        float nv = fminf(fmaxf(t0v, o0), fminf(t1v, o1));
        t0v = fminf(t0v, o0); t1v = nv;
    }
    // owners: split 0 -> q0, split 1 -> q1
    float contrib = (split < 2) ? crk * (t1v - t0v) : 0.0f;

#pragma unroll
    for (int o = 32; o > 0; o >>= 1) contrib += __shfl_down(contrib, o);
    if ((tid & 63) == 0) part[tid >> 6] = contrib;
    __syncthreads();
    if (tid == 0) {
        float s = 0.0f;
#pragma unroll
        for (int i = 0; i < 16; ++i) s += part[i];
        atomicAdd(out, s);
    }

    // ---- skeleton self-NN term, one block per batch ----
    if ((blockIdx.x & 63) == 0) {
        float v = 0.0f;
        if (tid < NSKEL) {
            float4 sq = sskl[tid];
            float b0 = BIG, b1 = BIG; int i0 = 0, i1 = 0;
            for (int jj = 0; jj < NSKEL; ++jj) {
                float4 c = sskl[jj];
                float s = c.w - 2.0f*(sq.x*c.x + sq.y*c.y + sq.z*c.z);
                if (s < b0)      { b1 = b0; i1 = i0; b0 = s; i0 = jj; }
                else if (s < b1) { b1 = s; i1 = jj; }
            }
            float4 c = sskl[i1];                 // knn_skele[..., 1]
            float dx = sq.x - c.x, dy = sq.y - c.y, dz = sq.z - c.z;
            v = sqrtf(dx*dx + dy*dy + dz*dz);
        }
#pragma unroll
        for (int o = 32; o > 0; o >>= 1) v += __shfl_down(v, o);
        if ((tid & 63) == 0 && tid < 128) atomicAdd(out, -0.5f * v);
    }
}

extern "C" void kernel_launch(void* const* d_in, const int* in_sizes, int n_in,
                              void* d_out, int out_size, void* d_ws, size_t ws_size,
                              hipStream_t stream) {
    const float* xyz  = (const float*)d_in[0];
    // d_in[1] = num_class (== NSKEL), compile-time constant here
    const float* skel = (const float*)d_in[2];
    float* out = (float*)d_out;

    hipMemsetAsync(out, 0, sizeof(float), stream);
    voronoi_kernel<<<BATCH * 64, 1024, 0, stream>>>(xyz, skel, out);
}